// Round 7
// baseline (125.101 us; speedup 1.0000x reference)
//
#include <hip/hip_runtime.h>
#include <math.h>

#define S_LEN   2048
#define D_MODEL 768
#define NH      12
#define DH      64
#define BATCH   2

typedef __attribute__((ext_vector_type(4)))  float f32x4;
typedef __attribute__((ext_vector_type(16))) float f32x16;
typedef __attribute__((ext_vector_type(8)))  short bf16x8;
typedef __attribute__((ext_vector_type(4)))  short short4v;
typedef __attribute__((ext_vector_type(2)))  unsigned u32x2;

__device__ __forceinline__ short f2bf(float f) {
    union { float f; unsigned u; } v; v.f = f;
    unsigned r = (v.u + 0x7FFFu + ((v.u >> 16) & 1u)) >> 16;
    return (short)r;
}
__device__ __forceinline__ float bf2f(short s) {
    union { unsigned u; float f; } v; v.u = ((unsigned)(unsigned short)s) << 16;
    return v.f;
}
__device__ __forceinline__ unsigned cvt_pk_bf16(float lo, float hi) {
    unsigned r;
    asm("v_cvt_pk_bf16_f32 %0, %1, %2" : "=v"(r) : "v"(lo), "v"(hi));
    return r;
}
__device__ __forceinline__ void perm32swap(unsigned &a, unsigned &b) {
    asm("v_permlane32_swap_b32 %0, %1" : "+v"(a), "+v"(b));
}

#define GLOAD_LDS16(gp, lp)                                                     \
    __builtin_amdgcn_global_load_lds(                                           \
        (const __attribute__((address_space(1))) void*)(gp),                    \
        (__attribute__((address_space(3))) void*)(lp), 16, 0, 0)

// ---------------------------------------------------------------------------
// convert x [B*S, 2304] fp32 -> bf16
// ---------------------------------------------------------------------------
__global__ __launch_bounds__(256) void convert_x_kernel(
    const float* __restrict__ x, short* __restrict__ xb)
{
    const size_t i = ((size_t)blockIdx.x * 256 + threadIdx.x) * 8;
    const f32x4 a = *(const f32x4*)(x + i);
    const f32x4 b = *(const f32x4*)(x + i + 4);
    bf16x8 r;
    r[0] = f2bf(a[0]); r[1] = f2bf(a[1]); r[2] = f2bf(a[2]); r[3] = f2bf(a[3]);
    r[4] = f2bf(b[0]); r[5] = f2bf(b[1]); r[6] = f2bf(b[2]); r[7] = f2bf(b[3]);
    *(bf16x8*)(xb + i) = r;
}

// ---------------------------------------------------------------------------
// convert+transpose W [768,768] fp32 -> Wt [n][k] bf16. grid (12,12,4)
// ---------------------------------------------------------------------------
__global__ __launch_bounds__(256) void convert_wt_kernel(
    const float* __restrict__ wq, const float* __restrict__ wk,
    const float* __restrict__ wv, const float* __restrict__ wc,
    short* __restrict__ wt)
{
    __shared__ float Ld[64][65];
    const int z = blockIdx.z;
    const float* W = (z == 0) ? wq : (z == 1) ? wk : (z == 2) ? wv : wc;
    short* dst = wt + (size_t)z * D_MODEL * D_MODEL;

    const int t = threadIdx.x;
    const int r0 = blockIdx.y * 64;
    const int c0 = blockIdx.x * 64;

#pragma unroll
    for (int i = 0; i < 4; ++i) {
        const int r = (t >> 4) + 16 * i;
        const int c = (t & 15) * 4;
        const float4 a = *(const float4*)(W + (size_t)(r0 + r) * D_MODEL + c0 + c);
        Ld[r][c + 0] = a.x; Ld[r][c + 1] = a.y; Ld[r][c + 2] = a.z; Ld[r][c + 3] = a.w;
    }
    __syncthreads();
#pragma unroll
    for (int i = 0; i < 4; ++i) {
        const int n = (t >> 4) + 16 * i;
        const int kq = (t & 15) * 4;
        short4v s4;
        s4[0] = f2bf(Ld[kq + 0][n]); s4[1] = f2bf(Ld[kq + 1][n]);
        s4[2] = f2bf(Ld[kq + 2][n]); s4[3] = f2bf(Ld[kq + 3][n]);
        *(short4v*)(dst + (size_t)(c0 + n) * D_MODEL + r0 + kq) = s4;
    }
}

// ---------------------------------------------------------------------------
// bf16 MFMA GEMM (m97 structure), unchanged.
// ---------------------------------------------------------------------------
__device__ __forceinline__ void gemm_bt_body(
    const short* __restrict__ A, int lda,
    const short* __restrict__ Bt,
    const float* __restrict__ bias,
    void* __restrict__ C, int ldc, bool out_bf16)
{
    __shared__ __align__(16) char ldsA[16384];
    __shared__ __align__(16) char ldsB[16384];

    const int t = threadIdx.x, lane = t & 63, w = t >> 6;
    const int l15 = lane & 15, l4 = lane >> 4;
    const int wr = w >> 1, wc = w & 1;
    const int row0 = blockIdx.y * 128, col0 = blockIdx.x * 128;

    const int srow = lane >> 3;
    const int sblk = (lane & 7) ^ srow;

    f32x4 acc[4][4];
#pragma unroll
    for (int i = 0; i < 4; ++i)
#pragma unroll
        for (int j = 0; j < 4; ++j) acc[i][j] = (f32x4){0.f, 0.f, 0.f, 0.f};

    for (int kt = 0; kt < 12; ++kt) {
        __syncthreads();
#pragma unroll
        for (int i = 0; i < 4; ++i) {
            const int row = i * 32 + w * 8 + srow;
            GLOAD_LDS16(A  + (size_t)(row0 + row) * lda + kt * 64 + sblk * 8,
                        ldsA + i * 4096 + w * 1024);
            GLOAD_LDS16(Bt + (size_t)(col0 + row) * D_MODEL + kt * 64 + sblk * 8,
                        ldsB + i * 4096 + w * 1024);
        }
        __syncthreads();

        bf16x8 af[4][2], bfr[4][2];
#pragma unroll
        for (int rb = 0; rb < 4; ++rb) {
            const int r = wr * 64 + rb * 16 + l15;
#pragma unroll
            for (int c = 0; c < 2; ++c)
                af[rb][c] = *(const bf16x8*)(ldsA + r * 128 + (((c * 4 + l4) ^ (r & 7)) << 4));
        }
#pragma unroll
        for (int cb = 0; cb < 4; ++cb) {
            const int r = wc * 64 + cb * 16 + l15;
#pragma unroll
            for (int c = 0; c < 2; ++c)
                bfr[cb][c] = *(const bf16x8*)(ldsB + r * 128 + (((c * 4 + l4) ^ (r & 7)) << 4));
        }
#pragma unroll
        for (int rb = 0; rb < 4; ++rb)
#pragma unroll
            for (int cb = 0; cb < 4; ++cb) {
                acc[rb][cb] = __builtin_amdgcn_mfma_f32_16x16x32_bf16(
                    af[rb][0], bfr[cb][0], acc[rb][cb], 0, 0, 0);
                acc[rb][cb] = __builtin_amdgcn_mfma_f32_16x16x32_bf16(
                    af[rb][1], bfr[cb][1], acc[rb][cb], 0, 0, 0);
            }
    }

#pragma unroll
    for (int cb = 0; cb < 4; ++cb) {
        const int col = col0 + wc * 64 + cb * 16 + l15;
        const float bv = bias[col];
#pragma unroll
        for (int rb = 0; rb < 4; ++rb)
#pragma unroll
            for (int r = 0; r < 4; ++r) {
                const int row = row0 + wr * 64 + rb * 16 + 4 * l4 + r;
                const float val = acc[rb][cb][r] + bv;
                if (out_bf16) ((short*)C)[(size_t)row * ldc + col] = f2bf(val);
                else          ((float*)C)[(size_t)row * ldc + col] = val;
            }
    }
}

__global__ __launch_bounds__(256) void qkv_gemm_kernel(
    const short* __restrict__ xb, const short* __restrict__ wt,
    const float* __restrict__ bq, const float* __restrict__ bk,
    const float* __restrict__ bv, short* __restrict__ qkv)
{
    const int which = blockIdx.z;
    const float* bias = (which == 0) ? bq : (which == 1) ? bk : bv;
    gemm_bt_body(xb + which * D_MODEL, 3 * D_MODEL,
                 wt + (size_t)which * D_MODEL * D_MODEL, bias,
                 qkv + (size_t)which * BATCH * S_LEN * D_MODEL, D_MODEL, true);
}

__global__ __launch_bounds__(256) void proj_gemm_kernel(
    const short* __restrict__ att, const short* __restrict__ wct,
    const float* __restrict__ bc, float* __restrict__ out)
{
    gemm_bt_body(att, D_MODEL, wct, bc, out, D_MODEL, false);
}

// ---------------------------------------------------------------------------
// Flash attention v5: flash-decode chunking. Grid (51, 12, 2), 256 thr, 4 waves.
// Chunks per qt = ceil((qt+1)/3); chunk covers <=6 key-tiles (384 keys).
// qt 0..2 (single chunk): write final. qt>=3: write unnormalized bf16 partial
// O [128][64] + per-row (m,l) fp32; attn_merge_kernel combines.
// Same swapped-operand 32x32x16 MFMA structure as R5/R6.
// ---------------------------------------------------------------------------
__global__ __launch_bounds__(256) void attn_mfma_kernel(
    const short* __restrict__ q, const short* __restrict__ k,
    const short* __restrict__ v, short* __restrict__ o,
    short* __restrict__ part, float* __restrict__ ml)
{
    __shared__ __align__(16) char bufK[2][8192];
    __shared__ __align__(16) char bufV[2][8192];

    const int t    = threadIdx.x;
    const int lane = t & 63;
    const int w    = t >> 6;
    const int l31  = lane & 31;
    const int hi   = lane >> 5;
    const int r7   = l31 & 7;

    // map x -> (qt, chunk): cum[qt] = 3*g*(g+1)/2 + r*(g+1), g=qt/3, r=qt%3
    const int x = blockIdx.x;
    int qt = 0;
    qt += (x >= 1);  qt += (x >= 2);  qt += (x >= 3);  qt += (x >= 5);
    qt += (x >= 7);  qt += (x >= 9);  qt += (x >= 12); qt += (x >= 15);
    qt += (x >= 18); qt += (x >= 22); qt += (x >= 26); qt += (x >= 30);
    qt += (x >= 35); qt += (x >= 40); qt += (x >= 45);
    const int g3  = qt / 3, rr3 = qt % 3;
    const int cum = 3 * g3 * (g3 + 1) / 2 + rr3 * (g3 + 1);
    const int chunk = x - cum;
    const bool multi = (qt >= 3);

    const int h  = blockIdx.y;
    const int b  = blockIdx.z;
    const int bh = h + 12 * b;
    const int slot = bh * 48 + (x - 3);          // valid only when multi

    const int nkt_total = 2 * qt + 2;
    const int t0 = chunk * 6;
    const int t1 = min(t0 + 6, nkt_total);

    const size_t base = (size_t)b * (S_LEN * D_MODEL) + h * DH;
    const int q0 = qt * 128 + w * 32;

    // ---- Q B-frags (col=l31=q, k=16*dc+8*hi+j), scale 1/8 folded in ----
    bf16x8 qf[4];
    {
        const short* qp = q + base + (size_t)(q0 + l31) * D_MODEL + 8 * hi;
#pragma unroll
        for (int dc = 0; dc < 4; ++dc) {
            bf16x8 r = *(const bf16x8*)(qp + 16 * dc);
#pragma unroll
            for (int j = 0; j < 8; ++j) r[j] = f2bf(bf2f(r[j]) * 0.125f);
            qf[dc] = r;
        }
    }

    f32x16 oT[2];
    oT[0] = (f32x16)(0.f); oT[1] = (f32x16)(0.f);
    float mrun = -1e30f, lrun = 0.f;

    const int srow = lane >> 3;
    const int sblk = (lane & 7) ^ srow;
    const int vk0  = (t >> 4) * 4;
    const int vd0  = (t & 15) * 4;

    short4v vreg[4];
    // ---- prologue: stage tile t0 ----
    {
#pragma unroll
        for (int i = 0; i < 4; ++i)
            vreg[i] = *(const short4v*)(
                v + base + (size_t)(t0 * 64 + vk0 + i) * D_MODEL + vd0);
#pragma unroll
        for (int i = 0; i < 2; ++i) {
            const int row = i * 32 + w * 8 + srow;
            GLOAD_LDS16(k + base + (size_t)(t0 * 64 + row) * D_MODEL + sblk * 8,
                        bufK[0] + i * 4096 + w * 1024);
        }
#pragma unroll
        for (int e = 0; e < 4; ++e) {
            const int dh = vd0 + e;
            short4v s4; s4[0] = vreg[0][e]; s4[1] = vreg[1][e]; s4[2] = vreg[2][e]; s4[3] = vreg[3][e];
            *(short4v*)(bufV[0] + dh * 128 + (((unsigned)(vk0 * 2)) ^ ((unsigned)(dh & 7) << 4))) = s4;
        }
        __syncthreads();
    }

    for (int kt = t0; kt < t1; ++kt) {
        const int cur = (kt - t0) & 1, nxt = cur ^ 1;
        const bool have_next = (kt + 1 < t1);

        // ---- issue next-tile loads first ----
        if (have_next) {
            const int tkn = kt + 1;
#pragma unroll
            for (int j = 0; j < 4; ++j)
                vreg[j] = *(const short4v*)(
                    v + base + (size_t)(tkn * 64 + vk0 + j) * D_MODEL + vd0);
#pragma unroll
            for (int j = 0; j < 2; ++j) {
                const int row = j * 32 + w * 8 + srow;
                GLOAD_LDS16(k + base + (size_t)(tkn * 64 + row) * D_MODEL + sblk * 8,
                            bufK[nxt] + (size_t)(j * 4096 + w * 1024));
            }
        }

        // ---- compute tile kt (wave-uniform causal skip) ----
        if (kt * 64 <= q0 + 31) {
            f32x16 cS[2];
#pragma unroll
            for (int s = 0; s < 2; ++s) {
                f32x16 acc = (f32x16)(0.f);
#pragma unroll
                for (int dc = 0; dc < 4; ++dc) {
                    const int row = 32 * s + l31;
                    const bf16x8 kf = *(const bf16x8*)(
                        bufK[cur] + row * 128 + (((unsigned)(32 * dc + 16 * hi)) ^ ((unsigned)r7 << 4)));
                    acc = __builtin_amdgcn_mfma_f32_32x32x16_bf16(kf, qf[dc], acc, 0, 0, 0);
                }
                cS[s] = acc;
            }

            if (kt * 64 + 63 > q0) {   // boundary tiles: causal mask
                const int qg = q0 + l31;
#pragma unroll
                for (int s = 0; s < 2; ++s)
#pragma unroll
                    for (int rg = 0; rg < 16; ++rg) {
                        const int key = kt * 64 + 32 * s + (rg & 3) + 8 * (rg >> 2) + 4 * hi;
                        if (key > qg) cS[s][rg] = -1e30f;
                    }
            }

            // online softmax, defer-max (THR=8)
            float pmax = -1e30f;
#pragma unroll
            for (int s = 0; s < 2; ++s)
#pragma unroll
                for (int rg = 0; rg < 16; ++rg) pmax = fmaxf(pmax, cS[s][rg]);
            pmax = fmaxf(pmax, __shfl_xor(pmax, 32));

            if (!__all(pmax - mrun <= 8.0f)) {
                const float mnew = fmaxf(mrun, pmax);
                const float corr = __expf(mrun - mnew);
                lrun *= corr;
#pragma unroll
                for (int d0 = 0; d0 < 2; ++d0)
#pragma unroll
                    for (int rg = 0; rg < 16; ++rg) oT[d0][rg] *= corr;
                mrun = mnew;
            }
            float psum = 0.f;
#pragma unroll
            for (int s = 0; s < 2; ++s)
#pragma unroll
                for (int rg = 0; rg < 16; ++rg) {
                    const float e = __expf(cS[s][rg] - mrun);
                    cS[s][rg] = e; psum += e;
                }
            psum += __shfl_xor(psum, 32);
            lrun += psum;

            // P -> bf16 B-frags in-register
            bf16x8 pfrag[4];
#pragma unroll
            for (int s = 0; s < 2; ++s)
#pragma unroll
                for (int tt = 0; tt < 2; ++tt) {
                    unsigned a0 = cvt_pk_bf16(cS[s][8 * tt + 0], cS[s][8 * tt + 1]);
                    unsigned a1 = cvt_pk_bf16(cS[s][8 * tt + 2], cS[s][8 * tt + 3]);
                    unsigned b0 = cvt_pk_bf16(cS[s][8 * tt + 4], cS[s][8 * tt + 5]);
                    unsigned b1 = cvt_pk_bf16(cS[s][8 * tt + 6], cS[s][8 * tt + 7]);
                    perm32swap(a0, b0);
                    perm32swap(a1, b1);
                    union { unsigned u[4]; bf16x8 v8; } pk;
                    pk.u[0] = a0; pk.u[1] = a1; pk.u[2] = b0; pk.u[3] = b1;
                    pfrag[2 * s + tt] = pk.v8;
                }

            // O^T += Vt . P
#pragma unroll
            for (int d0 = 0; d0 < 2; ++d0) {
                f32x16 acc = oT[d0];
#pragma unroll
                for (int c = 0; c < 4; ++c) {
                    const int row = 32 * d0 + l31;
                    const bf16x8 vf = *(const bf16x8*)(
                        bufV[cur] + row * 128 + (((unsigned)(32 * c + 16 * hi)) ^ ((unsigned)r7 << 4)));
                    acc = __builtin_amdgcn_mfma_f32_32x32x16_bf16(vf, pfrag[c], acc, 0, 0, 0);
                }
                oT[d0] = acc;
            }
        }

        // ---- write next V^T ----
        if (have_next) {
#pragma unroll
            for (int e = 0; e < 4; ++e) {
                const int dh = vd0 + e;
                short4v s4; s4[0] = vreg[0][e]; s4[1] = vreg[1][e]; s4[2] = vreg[2][e]; s4[3] = vreg[3][e];
                *(short4v*)(bufV[nxt] + dh * 128 + (((unsigned)(vk0 * 2)) ^ ((unsigned)(dh & 7) << 4))) = s4;
            }
        }
        __syncthreads();
    }

    // ---- epilogue: transpose O^T via wave-private LDS slab, then store ----
    if (multi && hi == 0) {
        ml[(size_t)slot * 256 + w * 32 + l31]       = mrun;
        ml[(size_t)slot * 256 + 128 + w * 32 + l31] = lrun;
    }
    const float scale = multi ? 1.f : (1.f / lrun);
    char* wbuf = &bufV[0][0] + w * 4096;   // 32x64 bf16 tile, per wave
#pragma unroll
    for (int d0 = 0; d0 < 2; ++d0)
#pragma unroll
        for (int gg = 0; gg < 4; ++gg) {
            u32x2 u2;
            u2[0] = cvt_pk_bf16(oT[d0][4 * gg + 0] * scale, oT[d0][4 * gg + 1] * scale);
            u2[1] = cvt_pk_bf16(oT[d0][4 * gg + 2] * scale, oT[d0][4 * gg + 3] * scale);
            const unsigned byteoff = ((unsigned)(16 * gg + 8 * hi + 64 * d0)) ^ ((unsigned)r7 << 4);
            *(u32x2*)(wbuf + l31 * 128 + byteoff) = u2;
        }
    // same-wave LDS RAW; compiler inserts lgkmcnt
#pragma unroll
    for (int it = 0; it < 4; ++it) {
        const int R = lane >> 1;
        const unsigned lb = ((unsigned)((lane & 1) * 16 + it * 32)) ^ ((unsigned)(R & 7) << 4);
        const bf16x8 vv = *(const bf16x8*)(wbuf + R * 128 + lb);
        const int col = (lane & 1) * 8 + it * 16;
        if (multi) {
            *(bf16x8*)(part + (size_t)slot * 8192 + (w * 32 + R) * 64 + col) = vv;
        } else {
            const int row = qt * 128 + w * 32 + R;
            *(bf16x8*)(o + base + (size_t)row * D_MODEL + col) = vv;
        }
    }
}

// ---------------------------------------------------------------------------
// Flash-decode merge for qt >= 3. Grid (13, 12, 2), 256 thr.
// Thread -> (row = t>>1, dh-half = (t&1)*32). 3 passes over ml to avoid
// runtime-indexed register arrays (scratch hazard).
// ---------------------------------------------------------------------------
__global__ __launch_bounds__(256) void attn_merge_kernel(
    const short* __restrict__ part, const float* __restrict__ ml,
    short* __restrict__ o)
{
    const int qt = 3 + (int)blockIdx.x;
    const int h = blockIdx.y, b = blockIdx.z;
    const int bh = h + 12 * b;
    const int g3 = qt / 3, rr3 = qt % 3;
    const int slot0 = bh * 48 + (3 * g3 * (g3 + 1) / 2 + rr3 * (g3 + 1)) - 3;
    const int nch = (qt + 3) / 3;

    const int t   = threadIdx.x;
    const int row = t >> 1;
    const int co  = (t & 1) * 32;

    float M = -1e30f;
    for (int c = 0; c < nch; ++c)
        M = fmaxf(M, ml[(size_t)(slot0 + c) * 256 + row]);
    float denom = 0.f;
    for (int c = 0; c < nch; ++c) {
        const float mc = ml[(size_t)(slot0 + c) * 256 + row];
        const float lc = ml[(size_t)(slot0 + c) * 256 + 128 + row];
        denom += __expf(mc - M) * lc;
    }
    const float inv = 1.f / denom;

    float acc[32];
#pragma unroll
    for (int i = 0; i < 32; ++i) acc[i] = 0.f;
    for (int c = 0; c < nch; ++c) {
        const float s = __expf(ml[(size_t)(slot0 + c) * 256 + row] - M) * inv;
        const short* p = part + (size_t)(slot0 + c) * 8192 + row * 64 + co;
#pragma unroll
        for (int vv = 0; vv < 4; ++vv) {
            const bf16x8 d = *(const bf16x8*)(p + vv * 8);
#pragma unroll
            for (int j = 0; j < 8; ++j) acc[vv * 8 + j] += s * bf2f(d[j]);
        }
    }

    const size_t base = (size_t)b * (S_LEN * D_MODEL) + h * DH;
    short* dst = o + base + (size_t)(qt * 128 + row) * D_MODEL + co;
#pragma unroll
    for (int vv = 0; vv < 4; ++vv) {
        bf16x8 d;
#pragma unroll
        for (int j = 0; j < 8; ++j) d[j] = f2bf(acc[vv * 8 + j]);
        *(bf16x8*)(dst + vv * 8) = d;
    }
}

extern "C" void kernel_launch(void* const* d_in, const int* in_sizes, int n_in,
                              void* d_out, int out_size, void* d_ws, size_t ws_size,
                              hipStream_t stream)
{
    const float* x  = (const float*)d_in[0];
    // d_in[1] = mask: exact causal triu -> analytic, not read
    const float* wq = (const float*)d_in[2];
    const float* bq = (const float*)d_in[3];
    const float* wk = (const float*)d_in[4];
    const float* bk = (const float*)d_in[5];
    const float* wv = (const float*)d_in[6];
    const float* bv = (const float*)d_in[7];
    const float* wc = (const float*)d_in[8];
    const float* bc = (const float*)d_in[9];
    float* out = (float*)d_out;

    const size_t nx  = (size_t)BATCH * S_LEN * 3 * D_MODEL;   // 9,437,184
    const size_t nw  = (size_t)D_MODEL * D_MODEL;
    const size_t nqv = (size_t)BATCH * S_LEN * D_MODEL;

    short* xb  = (short*)d_ws;
    short* wt  = xb + nx;
    short* qkv = wt + 4 * nw;
    short* att = qkv + 3 * nqv;
    float* ml  = (float*)(att + nqv);      // 1152 slots * 256 floats = 1.18 MB
    // attention partials (1152 slots * 16 KB = 18.87 MB) alias xb: qkv_gemm has
    // finished reading xb before attn runs; convert_x rewrites xb every launch.
    short* part = xb;

    dim3 blk(256);
    convert_x_kernel <<<dim3((unsigned)(nx / (256 * 8))), blk, 0, stream>>>(x, xb);
    convert_wt_kernel<<<dim3(12, 12, 4), blk, 0, stream>>>(wq, wk, wv, wc, wt);
    qkv_gemm_kernel  <<<dim3(6, 32, 3), blk, 0, stream>>>(xb, wt, bq, bk, bv, qkv);
    attn_mfma_kernel <<<dim3(51, NH, BATCH), blk, 0, stream>>>(
        qkv, qkv + nqv, qkv + 2 * nqv, att, part, ml);
    attn_merge_kernel<<<dim3(13, NH, BATCH), blk, 0, stream>>>(part, ml, att);
    proj_gemm_kernel <<<dim3(6, 32), blk, 0, stream>>>(att, wt + 3 * nw, bc, out);
}

// Round 8
// 103.454 us; speedup vs baseline: 1.2092x; 1.2092x over previous
//
#include <hip/hip_runtime.h>
#include <math.h>

#define S_LEN   2048
#define D_MODEL 768
#define NH      12
#define DH      64
#define BATCH   2

typedef __attribute__((ext_vector_type(4)))  float f32x4;
typedef __attribute__((ext_vector_type(16))) float f32x16;
typedef __attribute__((ext_vector_type(8)))  short bf16x8;
typedef __attribute__((ext_vector_type(4)))  short short4v;
typedef __attribute__((ext_vector_type(2)))  unsigned u32x2;

__device__ __forceinline__ short f2bf(float f) {
    union { float f; unsigned u; } v; v.f = f;
    unsigned r = (v.u + 0x7FFFu + ((v.u >> 16) & 1u)) >> 16;
    return (short)r;
}
__device__ __forceinline__ float bf2f(short s) {
    union { unsigned u; float f; } v; v.u = ((unsigned)(unsigned short)s) << 16;
    return v.f;
}
__device__ __forceinline__ unsigned cvt_pk_bf16(float lo, float hi) {
    unsigned r;
    asm("v_cvt_pk_bf16_f32 %0, %1, %2" : "=v"(r) : "v"(lo), "v"(hi));
    return r;
}
__device__ __forceinline__ void perm32swap(unsigned &a, unsigned &b) {
    asm("v_permlane32_swap_b32 %0, %1" : "+v"(a), "+v"(b));
}

#define GLOAD_LDS16(gp, lp)                                                     \
    __builtin_amdgcn_global_load_lds(                                           \
        (const __attribute__((address_space(1))) void*)(gp),                    \
        (__attribute__((address_space(3))) void*)(lp), 16, 0, 0)

// ---------------------------------------------------------------------------
// merged converts: blocks [0,4608) convert x fp32->bf16; [4608,5184) do W^T.
// ---------------------------------------------------------------------------
__global__ __launch_bounds__(256) void convert_xw_kernel(
    const float* __restrict__ x, short* __restrict__ xb,
    const float* __restrict__ wq, const float* __restrict__ wk,
    const float* __restrict__ wv, const float* __restrict__ wc,
    short* __restrict__ wt)
{
    const int bid = blockIdx.x;
    const int t = threadIdx.x;
    if (bid < 4608) {
        const size_t i = ((size_t)bid * 256 + t) * 8;
        const f32x4 a = *(const f32x4*)(x + i);
        const f32x4 b = *(const f32x4*)(x + i + 4);
        bf16x8 r;
        r[0] = f2bf(a[0]); r[1] = f2bf(a[1]); r[2] = f2bf(a[2]); r[3] = f2bf(a[3]);
        r[4] = f2bf(b[0]); r[5] = f2bf(b[1]); r[6] = f2bf(b[2]); r[7] = f2bf(b[3]);
        *(bf16x8*)(xb + i) = r;
        return;
    }
    __shared__ float Ld[64][65];
    const int rem = bid - 4608;             // 0..575
    const int z  = rem / 144;
    const int yy = (rem % 144) / 12;
    const int xx = rem % 12;
    const float* W = (z == 0) ? wq : (z == 1) ? wk : (z == 2) ? wv : wc;
    short* dst = wt + (size_t)z * D_MODEL * D_MODEL;
    const int r0 = yy * 64;                 // k range
    const int c0 = xx * 64;                 // n range

#pragma unroll
    for (int i = 0; i < 4; ++i) {
        const int r = (t >> 4) + 16 * i;
        const int c = (t & 15) * 4;
        const float4 a = *(const float4*)(W + (size_t)(r0 + r) * D_MODEL + c0 + c);
        Ld[r][c + 0] = a.x; Ld[r][c + 1] = a.y; Ld[r][c + 2] = a.z; Ld[r][c + 3] = a.w;
    }
    __syncthreads();
#pragma unroll
    for (int i = 0; i < 4; ++i) {
        const int n = (t >> 4) + 16 * i;
        const int kq = (t & 15) * 4;
        short4v s4;
        s4[0] = f2bf(Ld[kq + 0][n]); s4[1] = f2bf(Ld[kq + 1][n]);
        s4[2] = f2bf(Ld[kq + 2][n]); s4[3] = f2bf(Ld[kq + 3][n]);
        *(short4v*)(dst + (size_t)(c0 + n) * D_MODEL + r0 + kq) = s4;
    }
}

// ---------------------------------------------------------------------------
// bf16 MFMA GEMM (m97 structure). out_mode: 0 = fp32 row-major,
// 1 = bf16 row-major, 2 = bf16 TRANSPOSED per-head (Vt[bh][dh][s]).
// ---------------------------------------------------------------------------
__device__ __forceinline__ void gemm_bt_body(
    const short* __restrict__ A, int lda,
    const short* __restrict__ Bt,
    const float* __restrict__ bias,
    void* __restrict__ C, int ldc, int out_mode)
{
    __shared__ __align__(16) char ldsA[16384];
    __shared__ __align__(16) char ldsB[16384];

    const int t = threadIdx.x, lane = t & 63, w = t >> 6;
    const int l15 = lane & 15, l4 = lane >> 4;
    const int wr = w >> 1, wc = w & 1;
    const int row0 = blockIdx.y * 128, col0 = blockIdx.x * 128;

    const int srow = lane >> 3;
    const int sblk = (lane & 7) ^ srow;

    f32x4 acc[4][4];
#pragma unroll
    for (int i = 0; i < 4; ++i)
#pragma unroll
        for (int j = 0; j < 4; ++j) acc[i][j] = (f32x4){0.f, 0.f, 0.f, 0.f};

    for (int kt = 0; kt < 12; ++kt) {
        __syncthreads();
#pragma unroll
        for (int i = 0; i < 4; ++i) {
            const int row = i * 32 + w * 8 + srow;
            GLOAD_LDS16(A  + (size_t)(row0 + row) * lda + kt * 64 + sblk * 8,
                        ldsA + i * 4096 + w * 1024);
            GLOAD_LDS16(Bt + (size_t)(col0 + row) * D_MODEL + kt * 64 + sblk * 8,
                        ldsB + i * 4096 + w * 1024);
        }
        __syncthreads();

        bf16x8 af[4][2], bfr[4][2];
#pragma unroll
        for (int rb = 0; rb < 4; ++rb) {
            const int r = wr * 64 + rb * 16 + l15;
#pragma unroll
            for (int c = 0; c < 2; ++c)
                af[rb][c] = *(const bf16x8*)(ldsA + r * 128 + (((c * 4 + l4) ^ (r & 7)) << 4));
        }
#pragma unroll
        for (int cb = 0; cb < 4; ++cb) {
            const int r = wc * 64 + cb * 16 + l15;
#pragma unroll
            for (int c = 0; c < 2; ++c)
                bfr[cb][c] = *(const bf16x8*)(ldsB + r * 128 + (((c * 4 + l4) ^ (r & 7)) << 4));
        }
        __builtin_amdgcn_s_setprio(1);
#pragma unroll
        for (int rb = 0; rb < 4; ++rb)
#pragma unroll
            for (int cb = 0; cb < 4; ++cb) {
                acc[rb][cb] = __builtin_amdgcn_mfma_f32_16x16x32_bf16(
                    af[rb][0], bfr[cb][0], acc[rb][cb], 0, 0, 0);
                acc[rb][cb] = __builtin_amdgcn_mfma_f32_16x16x32_bf16(
                    af[rb][1], bfr[cb][1], acc[rb][cb], 0, 0, 0);
            }
        __builtin_amdgcn_s_setprio(0);
    }

#pragma unroll
    for (int cb = 0; cb < 4; ++cb) {
        const int col = col0 + wc * 64 + cb * 16 + l15;
        const float bv = bias[col];
        if (out_mode == 2) {
            // Vt[((b*12+h)*64+dh)][s], s = row; pack 4 consecutive s
            const int h  = col >> 6, dh = col & 63;
#pragma unroll
            for (int rb = 0; rb < 4; ++rb) {
                const int row = row0 + wr * 64 + rb * 16 + 4 * l4;
                const int b   = row >> 11, s0 = row & 2047;
                short4v s4;
                s4[0] = f2bf(acc[rb][cb][0] + bv);
                s4[1] = f2bf(acc[rb][cb][1] + bv);
                s4[2] = f2bf(acc[rb][cb][2] + bv);
                s4[3] = f2bf(acc[rb][cb][3] + bv);
                *(short4v*)((short*)C + ((size_t)((b * 12 + h) * 64 + dh)) * S_LEN + s0) = s4;
            }
        } else {
#pragma unroll
            for (int rb = 0; rb < 4; ++rb)
#pragma unroll
                for (int r = 0; r < 4; ++r) {
                    const int row = row0 + wr * 64 + rb * 16 + 4 * l4 + r;
                    const float val = acc[rb][cb][r] + bv;
                    if (out_mode == 1) ((short*)C)[(size_t)row * ldc + col] = f2bf(val);
                    else               ((float*)C)[(size_t)row * ldc + col] = val;
                }
        }
    }
}

__global__ __launch_bounds__(256) void qkv_gemm_kernel(
    const short* __restrict__ xb, const short* __restrict__ wt,
    const float* __restrict__ bq, const float* __restrict__ bk,
    const float* __restrict__ bv, short* __restrict__ qkv)
{
    const int which = blockIdx.z;
    const float* bias = (which == 0) ? bq : (which == 1) ? bk : bv;
    gemm_bt_body(xb + which * D_MODEL, 3 * D_MODEL,
                 wt + (size_t)which * D_MODEL * D_MODEL, bias,
                 qkv + (size_t)which * BATCH * S_LEN * D_MODEL, D_MODEL,
                 (which == 2) ? 2 : 1);
}

__global__ __launch_bounds__(256) void proj_gemm_kernel(
    const short* __restrict__ att, const short* __restrict__ wct,
    const float* __restrict__ bc, float* __restrict__ out)
{
    gemm_bt_body(att, D_MODEL, wct, bc, out, D_MODEL, 0);
}

// ---------------------------------------------------------------------------
// Flash attention v6: split-KV (R6 base) with Vt via global_load_lds.
// Grid (16,12,2), block 512 = 8 waves. Group g = w>>2 handles key tiles
// [g*(qt+1), (g+1)*(qt+1)); wave w4 = w&3 owns q-rows [qt*128+w4*32, +32).
// K LDS [key][d], Vt LDS [dh][key] — both staged by global_load_lds with
// pre-swizzled source, read with XOR (row&7)<<4, both conflict-free.
// S^T = mfma(K,Q); O^T = mfma(Vt,P); P in-register via cvt_pk+permlane32.
// Group 1 publishes (m,l,O^T) via LDS; group 0 merges + stores.
// ---------------------------------------------------------------------------
__global__ __launch_bounds__(512, 4) void attn_mfma_kernel(
    const short* __restrict__ q, const short* __restrict__ k,
    const short* __restrict__ vt, short* __restrict__ o)
{
    __shared__ __align__(16) char bufK[2][2][8192];   // [group][dbuf]
    __shared__ __align__(16) char bufV[2][2][8192];
    __shared__ float mlx[2][128];

    const int t    = threadIdx.x;
    const int lane = t & 63;
    const int w    = t >> 6;
    const int g    = w >> 2;
    const int w4   = w & 3;
    const int l31  = lane & 31;
    const int hi   = lane >> 5;
    const int r7   = l31 & 7;

    const int h  = blockIdx.y;
    const int b  = blockIdx.z;
    const int bh = h + 12 * b;
    const int qt = (bh >= 16) ? (15 - (int)blockIdx.x) : (int)blockIdx.x;
    const int nt = qt + 1;

    const size_t base   = (size_t)b * (S_LEN * D_MODEL) + h * DH;
    const size_t vtbase = (size_t)bh * DH * S_LEN;     // Vt rows for this head
    const int q0 = qt * 128 + w4 * 32;

    // ---- Q B-frags (col=l31=q, k=16*dc+8*hi+j), scale 1/8 folded in ----
    bf16x8 qf[4];
    {
        const short* qp = q + base + (size_t)(q0 + l31) * D_MODEL + 8 * hi;
#pragma unroll
        for (int dc = 0; dc < 4; ++dc) {
            bf16x8 r = *(const bf16x8*)(qp + 16 * dc);
#pragma unroll
            for (int j = 0; j < 8; ++j) r[j] = f2bf(bf2f(r[j]) * 0.125f);
            qf[dc] = r;
        }
    }

    f32x16 oT[2];
    oT[0] = (f32x16)(0.f); oT[1] = (f32x16)(0.f);
    float mrun = -1e30f, lrun = 0.f;

    const int srow = lane >> 3;
    const int sblk = (lane & 7) ^ srow;

    // ---- prologue: stage this group's tile 0 (K + Vt via gload_lds) ----
    {
        const int tk0 = g * nt;
#pragma unroll
        for (int i = 0; i < 2; ++i) {
            const int row = i * 32 + w4 * 8 + srow;
            GLOAD_LDS16(k  + base   + (size_t)(tk0 * 64 + row) * D_MODEL + sblk * 8,
                        bufK[g][0] + i * 4096 + w4 * 1024);
            GLOAD_LDS16(vt + vtbase + (size_t)row * S_LEN + tk0 * 64 + sblk * 8,
                        bufV[g][0] + i * 4096 + w4 * 1024);
        }
        __syncthreads();
    }

    for (int i = 0; i < nt; ++i) {
        const int cur = i & 1, nxt = cur ^ 1;
        const bool have_next = (i + 1 < nt);
        const int tk = g * nt + i;

        // ---- issue next-tile loads first (hide HBM under compute) ----
        if (have_next) {
            const int tkn = tk + 1;
#pragma unroll
            for (int j = 0; j < 2; ++j) {
                const int row = j * 32 + w4 * 8 + srow;
                GLOAD_LDS16(k  + base   + (size_t)(tkn * 64 + row) * D_MODEL + sblk * 8,
                            bufK[g][nxt] + (size_t)(j * 4096 + w4 * 1024));
                GLOAD_LDS16(vt + vtbase + (size_t)row * S_LEN + tkn * 64 + sblk * 8,
                            bufV[g][nxt] + (size_t)(j * 4096 + w4 * 1024));
            }
        }

        // ---- compute tile tk (wave-uniform causal skip) ----
        if (tk * 64 <= q0 + 31) {
            f32x16 cS[2];
            __builtin_amdgcn_s_setprio(1);
#pragma unroll
            for (int s = 0; s < 2; ++s) {
                f32x16 acc = (f32x16)(0.f);
#pragma unroll
                for (int dc = 0; dc < 4; ++dc) {
                    const int row = 32 * s + l31;
                    const bf16x8 kf = *(const bf16x8*)(
                        bufK[g][cur] + row * 128 + (((unsigned)(32 * dc + 16 * hi)) ^ ((unsigned)r7 << 4)));
                    acc = __builtin_amdgcn_mfma_f32_32x32x16_bf16(kf, qf[dc], acc, 0, 0, 0);
                }
                cS[s] = acc;
            }
            __builtin_amdgcn_s_setprio(0);

            if (tk * 64 + 63 > q0) {   // boundary tiles: causal mask
                const int qg = q0 + l31;
#pragma unroll
                for (int s = 0; s < 2; ++s)
#pragma unroll
                    for (int rg = 0; rg < 16; ++rg) {
                        const int key = tk * 64 + 32 * s + (rg & 3) + 8 * (rg >> 2) + 4 * hi;
                        if (key > qg) cS[s][rg] = -1e30f;
                    }
            }

            // online softmax, defer-max (THR=8)
            float pmax = -1e30f;
#pragma unroll
            for (int s = 0; s < 2; ++s)
#pragma unroll
                for (int rg = 0; rg < 16; ++rg) pmax = fmaxf(pmax, cS[s][rg]);
            pmax = fmaxf(pmax, __shfl_xor(pmax, 32));

            if (!__all(pmax - mrun <= 8.0f)) {
                const float mnew = fmaxf(mrun, pmax);
                const float corr = __expf(mrun - mnew);
                lrun *= corr;
#pragma unroll
                for (int d0 = 0; d0 < 2; ++d0)
#pragma unroll
                    for (int rg = 0; rg < 16; ++rg) oT[d0][rg] *= corr;
                mrun = mnew;
            }
            float psum = 0.f;
#pragma unroll
            for (int s = 0; s < 2; ++s)
#pragma unroll
                for (int rg = 0; rg < 16; ++rg) {
                    const float e = __expf(cS[s][rg] - mrun);
                    cS[s][rg] = e; psum += e;
                }
            psum += __shfl_xor(psum, 32);
            lrun += psum;

            // P -> bf16 B-frags in-register
            bf16x8 pfrag[4];
#pragma unroll
            for (int s = 0; s < 2; ++s)
#pragma unroll
                for (int tt = 0; tt < 2; ++tt) {
                    unsigned a0 = cvt_pk_bf16(cS[s][8 * tt + 0], cS[s][8 * tt + 1]);
                    unsigned a1 = cvt_pk_bf16(cS[s][8 * tt + 2], cS[s][8 * tt + 3]);
                    unsigned b0 = cvt_pk_bf16(cS[s][8 * tt + 4], cS[s][8 * tt + 5]);
                    unsigned b1 = cvt_pk_bf16(cS[s][8 * tt + 6], cS[s][8 * tt + 7]);
                    perm32swap(a0, b0);
                    perm32swap(a1, b1);
                    union { unsigned u[4]; bf16x8 v8; } pk;
                    pk.u[0] = a0; pk.u[1] = a1; pk.u[2] = b0; pk.u[3] = b1;
                    pfrag[2 * s + tt] = pk.v8;
                }

            // O^T += Vt . P
            __builtin_amdgcn_s_setprio(1);
#pragma unroll
            for (int d0 = 0; d0 < 2; ++d0) {
                f32x16 acc = oT[d0];
#pragma unroll
                for (int c = 0; c < 4; ++c) {
                    const int row = 32 * d0 + l31;
                    const bf16x8 vf = *(const bf16x8*)(
                        bufV[g][cur] + row * 128 + (((unsigned)(32 * c + 16 * hi)) ^ ((unsigned)r7 << 4)));
                    acc = __builtin_amdgcn_mfma_f32_32x32x16_bf16(vf, pfrag[c], acc, 0, 0, 0);
                }
                oT[d0] = acc;
            }
            __builtin_amdgcn_s_setprio(0);
        }
        __syncthreads();
    }

    // ---- group 1 publishes partials (bufK reused as exchange buffer) ----
    if (g == 1) {
        float* ex = (float*)(&bufK[0][0][0]) + w4 * 2048;
#pragma unroll
        for (int d0 = 0; d0 < 2; ++d0)
#pragma unroll
            for (int rg = 0; rg < 16; ++rg)
                ex[(d0 * 16 + rg) * 64 + lane] = oT[d0][rg];
        if (hi == 0) {
            mlx[0][w4 * 32 + l31] = mrun;
            mlx[1][w4 * 32 + l31] = lrun;
        }
    }
    __syncthreads();

    // ---- group 0: flash-decode combine, normalize, transpose, store ----
    if (g == 0) {
        const float m1  = mlx[0][w4 * 32 + l31];
        const float l1v = mlx[1][w4 * 32 + l31];
        const float M   = fmaxf(mrun, m1);
        const float a0  = __expf(mrun - M);
        const float a1  = __expf(m1 - M);
        const float inv = 1.f / (a0 * lrun + a1 * l1v);
        const float* ex = (const float*)(&bufK[0][0][0]) + w4 * 2048;

        char* wbuf = (char*)(&bufV[0][0][0]) + w4 * 4096;   // 32x64 bf16 tile
#pragma unroll
        for (int d0 = 0; d0 < 2; ++d0)
#pragma unroll
            for (int gg = 0; gg < 4; ++gg) {
                float c0v = (a0 * oT[d0][4 * gg + 0] + a1 * ex[(d0 * 16 + 4 * gg + 0) * 64 + lane]) * inv;
                float c1v = (a0 * oT[d0][4 * gg + 1] + a1 * ex[(d0 * 16 + 4 * gg + 1) * 64 + lane]) * inv;
                float c2v = (a0 * oT[d0][4 * gg + 2] + a1 * ex[(d0 * 16 + 4 * gg + 2) * 64 + lane]) * inv;
                float c3v = (a0 * oT[d0][4 * gg + 3] + a1 * ex[(d0 * 16 + 4 * gg + 3) * 64 + lane]) * inv;
                u32x2 u2;
                u2[0] = cvt_pk_bf16(c0v, c1v);
                u2[1] = cvt_pk_bf16(c2v, c3v);
                const unsigned byteoff = ((unsigned)(16 * gg + 8 * hi + 64 * d0)) ^ ((unsigned)r7 << 4);
                *(u32x2*)(wbuf + l31 * 128 + byteoff) = u2;
            }
        // same-wave LDS RAW; compiler inserts lgkmcnt
#pragma unroll
        for (int it = 0; it < 4; ++it) {
            const int R = lane >> 1;
            const unsigned lb = ((unsigned)((lane & 1) * 16 + it * 32)) ^ ((unsigned)(R & 7) << 4);
            const bf16x8 vv = *(const bf16x8*)(wbuf + R * 128 + lb);
            const int row = qt * 128 + w4 * 32 + R;
            const int col = (lane & 1) * 8 + it * 16;
            *(bf16x8*)(o + base + (size_t)row * D_MODEL + col) = vv;
        }
    }
}

extern "C" void kernel_launch(void* const* d_in, const int* in_sizes, int n_in,
                              void* d_out, int out_size, void* d_ws, size_t ws_size,
                              hipStream_t stream)
{
    const float* x  = (const float*)d_in[0];
    // d_in[1] = mask: exact causal triu -> analytic, not read
    const float* wq = (const float*)d_in[2];
    const float* bq = (const float*)d_in[3];
    const float* wk = (const float*)d_in[4];
    const float* bk = (const float*)d_in[5];
    const float* wv = (const float*)d_in[6];
    const float* bv = (const float*)d_in[7];
    const float* wc = (const float*)d_in[8];
    const float* bc = (const float*)d_in[9];
    float* out = (float*)d_out;

    const size_t nx  = (size_t)BATCH * S_LEN * 3 * D_MODEL;
    const size_t nw  = (size_t)D_MODEL * D_MODEL;
    const size_t nqv = (size_t)BATCH * S_LEN * D_MODEL;

    short* xb  = (short*)d_ws;
    short* wt  = xb + nx;
    short* qkv = wt + 4 * nw;        // q | k | Vt (Vt in transposed layout)
    short* att = qkv + 3 * nqv;

    dim3 blk(256);
    convert_xw_kernel<<<dim3(4608 + 576), blk, 0, stream>>>(x, xb, wq, wk, wv, wc, wt);
    qkv_gemm_kernel  <<<dim3(6, 32, 3), blk, 0, stream>>>(xb, wt, bq, bk, bv, qkv);
    attn_mfma_kernel <<<dim3(16, NH, BATCH), dim3(512), 0, stream>>>(
        qkv, qkv + nqv, qkv + 2 * nqv, att);
    proj_gemm_kernel <<<dim3(6, 32), blk, 0, stream>>>(att, wt + 3 * nw, bc, out);
}